// Round 4
// baseline (304.834 us; speedup 1.0000x reference)
//
#include <hip/hip_runtime.h>

typedef unsigned long long u64;

#define N_DET 4096
#define NW 64               // 4096 bits = 64 u64 words
#define IOU_TR 0.3f
#define SCORE_TR 0.1f
#define EPS 1e-9f

// ---------------------------------------------------------------------------
// ws layout:
//   rows   : 4096*8 f32   (sorted detection rows)            128 KB
//   soa    : 7*4096 f32   (lox,loy,loz,hix,hiy,hiz,vol)      112 KB
//   valid  : 64 u64
//   keep   : 64 u64
//   D      : 4096 u64     (diagonal words: D[i] = word (i>>6) of row i) 32 KB
//   T      : 64*4096 u64  (TRANSPOSED sup bitmatrix: T[w][i])  2 MB
// T[w*4096+i] = word w of suppression row i (strictly upper: bits j>i only)
// ---------------------------------------------------------------------------

__device__ inline u64 shfl64(u64 v, int src) {
    int lo = __shfl((int)(unsigned)(v & 0xffffffffull), src, 64);
    int hi = __shfl((int)(unsigned)(v >> 32), src, 64);
    return ((u64)(unsigned)hi << 32) | (unsigned)lo;
}

// K1: stable descending sort by rank-counting + scatter rows & box SoA.
__global__ void k_sort(const float* __restrict__ res, float* __restrict__ rows,
                       float* __restrict__ soa) {
    __shared__ float s_scores[N_DET];
    int tid = threadIdx.x;
    int gid = blockIdx.x * 256 + tid;
    for (int j = tid; j < N_DET; j += 256) s_scores[j] = res[j * 8];
    __syncthreads();
    float s = s_scores[gid];
    int rank = 0;
    for (int j = 0; j < N_DET; ++j) {
        float sj = s_scores[j];
        rank += (sj > s) || (sj == s && j < gid);
    }
    float4 a = *(const float4*)(res + gid * 8);
    float4 b = *(const float4*)(res + gid * 8 + 4);
    *(float4*)(rows + rank * 8)     = a;
    *(float4*)(rows + rank * 8 + 4) = b;
    // a = (score, class, cx, cy); b = (cz, dx, dy, dz)
    float cx = a.z, cy = a.w, cz = b.x, dx = b.y, dy = b.z, dz = b.w;
    soa[0 * N_DET + rank] = cx - dx * 0.5f;
    soa[1 * N_DET + rank] = cy - dy * 0.5f;
    soa[2 * N_DET + rank] = cz - dz * 0.5f;
    soa[3 * N_DET + rank] = cx + dx * 0.5f;
    soa[4 * N_DET + rank] = cy + dy * 0.5f;
    soa[5 * N_DET + rank] = cz + dz * 0.5f;
    soa[6 * N_DET + rank] = (dx * dy) * dz;   // np.prod order: ((dx*dy)*dz)
}

// K2: validity ballot over sorted scores -> 64 words.
__global__ void k_valid(const float* __restrict__ rows,
                        u64* __restrict__ valid) {
    int gid = blockIdx.x * 64 + threadIdx.x;
    bool v = rows[gid * 8] >= SCORE_TR;
    u64 m = __ballot(v);
    if (threadIdx.x == 0) valid[blockIdx.x] = m;
}

// K3: suppression bitmatrix (transposed) + diagonal words.
__global__ void k_sup(const float* __restrict__ soa,
                      u64* __restrict__ T, u64* __restrict__ D) {
    int lane = threadIdx.x & 63;
    int wave = threadIdx.x >> 6;
    int i = blockIdx.x * 4 + wave;
    float ilox = soa[0 * N_DET + i], iloy = soa[1 * N_DET + i], iloz = soa[2 * N_DET + i];
    float ihix = soa[3 * N_DET + i], ihiy = soa[4 * N_DET + i], ihiz = soa[5 * N_DET + i];
    float ivol = soa[6 * N_DET + i];
    for (int w = 0; w < NW; ++w) {
        int j = w * 64 + lane;
        float lox = soa[0 * N_DET + j], loy = soa[1 * N_DET + j], loz = soa[2 * N_DET + j];
        float hix = soa[3 * N_DET + j], hiy = soa[4 * N_DET + j], hiz = soa[5 * N_DET + j];
        float vol = soa[6 * N_DET + j];
        float ix = fminf(ihix, hix) - fmaxf(ilox, lox); ix = fmaxf(ix, 0.0f);
        float iy = fminf(ihiy, hiy) - fmaxf(iloy, loy); iy = fmaxf(iy, 0.0f);
        float iz = fminf(ihiz, hiz) - fmaxf(iloz, loz); iz = fmaxf(iz, 0.0f);
        float inter = (ix * iy) * iz;                 // ((x*y)*z) like np.prod
        float uni = ivol + vol - inter;               // (vol_i+vol_j)-inter
        float iou = inter / (uni + EPS);              // IEEE div (HIP default CR)
        bool sb = (iou > IOU_TR) && (j > i);
        u64 m = __ballot(sb);
        if (lane == 0) {
            T[(size_t)w * N_DET + i] = m;
            if (w == (i >> 6)) D[i] = m;              // diagonal word of row i
        }
    }
}

// K4: serial greedy scan. ONE wave, all-VALU chain, no per-bit cross-lane ops.
// Lane l owns act word l (T stream per lane); ALL lanes mirror the current
// word `aw` and chain it with uniformly-loaded diagonal rows (D). Strict
// upper-triangularity => aw at word end == keep word w. One shfl per word.
#define BIT1(K, R, Dg) {                                              \
    u64 m_ = (u64)(((long long)(aw << (63 - (K)))) >> 63);            \
    aw  &= ~((Dg) & m_);                                              \
    act &= ~((R)  & m_); }

#define QUAD4(J) {                                                    \
    ulonglong4 r_ = s##J; s##J = sn[J];                               \
    ulonglong4 g_ = e##J; e##J = dn[J];                               \
    BIT1(4*(J)+0, r_.x, g_.x) BIT1(4*(J)+1, r_.y, g_.y)               \
    BIT1(4*(J)+2, r_.z, g_.z) BIT1(4*(J)+3, r_.w, g_.w) }

__global__ void __launch_bounds__(64, 1)
k_scan(const u64* __restrict__ T, const u64* __restrict__ D,
       const u64* __restrict__ valid, u64* __restrict__ keep) {
    const int lane = threadIdx.x;
    const ulonglong4* sp = (const ulonglong4*)(T + (size_t)lane * N_DET); // per-lane stream
    const ulonglong4* dq = (const ulonglong4*)D;                          // uniform diag
    u64 act = valid[lane];
    u64 keepw = 0;

    // prefill word 0
    ulonglong4 s0 = sp[0],  s1 = sp[1],  s2 = sp[2],  s3 = sp[3],
               s4 = sp[4],  s5 = sp[5],  s6 = sp[6],  s7 = sp[7],
               s8 = sp[8],  s9 = sp[9],  s10 = sp[10], s11 = sp[11],
               s12 = sp[12], s13 = sp[13], s14 = sp[14], s15 = sp[15];
    ulonglong4 e0 = dq[0],  e1 = dq[1],  e2 = dq[2],  e3 = dq[3],
               e4 = dq[4],  e5 = dq[5],  e6 = dq[6],  e7 = dq[7],
               e8 = dq[8],  e9 = dq[9],  e10 = dq[10], e11 = dq[11],
               e12 = dq[12], e13 = dq[13], e14 = dq[14], e15 = dq[15];

    for (int w = 0; w < NW; ++w) {
        u64 aw = shfl64(act, w);                 // broadcast owner lane's word
        const int wn = (w + 1) & 63;             // refill word (wraps; tail unused)
        const ulonglong4* sn = sp + (size_t)wn * 16;
        const ulonglong4* dn = dq + (size_t)wn * 16;
        QUAD4(0)  QUAD4(1)  QUAD4(2)  QUAD4(3)
        QUAD4(4)  QUAD4(5)  QUAD4(6)  QUAD4(7)
        QUAD4(8)  QUAD4(9)  QUAD4(10) QUAD4(11)
        QUAD4(12) QUAD4(13) QUAD4(14) QUAD4(15)
        keepw = (lane == w) ? aw : keepw;        // aw is final keep word w
    }
    keep[lane] = keepw;
}

// K5: gate rows by keep mask.
__global__ void k_out(const float* __restrict__ rows,
                      const u64* __restrict__ keep,
                      float* __restrict__ out) {
    int i = blockIdx.x * 256 + threadIdx.x;   // one detection per thread
    bool kp = (keep[i >> 6] >> (i & 63)) & 1ull;
    float4 a = kp ? ((const float4*)rows)[i * 2]     : make_float4(0.f, 0.f, 0.f, 0.f);
    float4 b = kp ? ((const float4*)rows)[i * 2 + 1] : make_float4(0.f, 0.f, 0.f, 0.f);
    ((float4*)out)[i * 2]     = a;
    ((float4*)out)[i * 2 + 1] = b;
}

extern "C" void kernel_launch(void* const* d_in, const int* in_sizes, int n_in,
                              void* d_out, int out_size, void* d_ws, size_t ws_size,
                              hipStream_t stream) {
    const float* res = (const float*)d_in[0];
    float* out = (float*)d_out;

    float* rows = (float*)d_ws;                       // 32768 f32
    float* soa  = rows + N_DET * 8;                   // 28672 f32
    u64* valid = (u64*)(soa + 7 * N_DET);
    u64* keep  = valid + NW;
    u64* D     = keep + NW;                           // 4096 u64 (diag words)
    u64* T     = D + N_DET;                           // 64*4096 u64 (transposed)

    k_sort <<<N_DET / 256, 256, 0, stream>>>(res, rows, soa);
    k_valid<<<NW, 64, 0, stream>>>(rows, valid);
    k_sup  <<<N_DET / 4, 256, 0, stream>>>(soa, T, D);
    k_scan <<<1, 64, 0, stream>>>(T, D, valid, keep);
    k_out  <<<N_DET / 256, 256, 0, stream>>>(rows, keep, out);
}

// Round 5
// 212.624 us; speedup vs baseline: 1.4337x; 1.4337x over previous
//
#include <hip/hip_runtime.h>

typedef unsigned long long u64;

#define N_DET 4096
#define NW 64               // 4096 bits = 64 u64 words
#define IOU_TR 0.3f
#define SCORE_TR 0.1f
#define EPS 1e-9f

// ---------------------------------------------------------------------------
// ws layout:
//   rows : 4096*8 f32   (sorted detection rows)            128 KB
//   soa  : 7*4096 f32   (lox,loy,loz,hix,hiy,hiz,vol)      112 KB
//   T    : 64*4096 u64  T[w][i] = word w of suppression row i (bits j>i only)
// Scan lane l streams T[l][i] (contiguous per lane). Diagonal words are
// recovered from the stream registers via v_readlane (lane = w), so no
// separate D array is needed.
// ---------------------------------------------------------------------------

__device__ __forceinline__ u64 rl64(u64 v, int l) {
    unsigned lo = __builtin_amdgcn_readlane((unsigned)v, l);
    unsigned hi = __builtin_amdgcn_readlane((unsigned)(v >> 32), l);
    return ((u64)hi << 32) | lo;
}

// K1: stable descending rank sort. 256 blocks x 256 thr; 16 rows/block,
// 16 threads per row each counting a 256-wide j-chunk, shfl_xor reduce.
__global__ void __launch_bounds__(256) k_sort(const float* __restrict__ res,
                                              float* __restrict__ rows,
                                              float* __restrict__ soa) {
    __shared__ float s[N_DET];
    int tid = threadIdx.x;
    for (int j = tid; j < N_DET; j += 256) s[j] = res[j * 8];
    __syncthreads();
    int r = tid >> 4, c = tid & 15;
    int gi = blockIdx.x * 16 + r;
    float sc = s[gi];
    int part = 0;
    int j0 = c * 256;
    for (int j = j0; j < j0 + 256; ++j) {
        float sj = s[j];
        part += (sj > sc) || (sj == sc && j < gi);
    }
    part += __shfl_xor(part, 1, 64);
    part += __shfl_xor(part, 2, 64);
    part += __shfl_xor(part, 4, 64);
    part += __shfl_xor(part, 8, 64);
    if (c == 0) {
        int rank = part;
        float4 a = *(const float4*)(res + gi * 8);
        float4 b = *(const float4*)(res + gi * 8 + 4);
        *(float4*)(rows + rank * 8)     = a;
        *(float4*)(rows + rank * 8 + 4) = b;
        // a = (score, class, cx, cy); b = (cz, dx, dy, dz)
        float cx = a.z, cy = a.w, cz = b.x, dx = b.y, dy = b.z, dz = b.w;
        soa[0 * N_DET + rank] = cx - dx * 0.5f;
        soa[1 * N_DET + rank] = cy - dy * 0.5f;
        soa[2 * N_DET + rank] = cz - dz * 0.5f;
        soa[3 * N_DET + rank] = cx + dx * 0.5f;
        soa[4 * N_DET + rank] = cy + dy * 0.5f;
        soa[5 * N_DET + rank] = cz + dz * 0.5f;
        soa[6 * N_DET + rank] = (dx * dy) * dz;   // np.prod order ((dx*dy)*dz)
    }
}

// K2: suppression bitmatrix T[w][i]. One wave per row i; 64 ballots.
__global__ void k_sup(const float* __restrict__ soa, u64* __restrict__ T) {
    int lane = threadIdx.x & 63;
    int wave = threadIdx.x >> 6;
    int i = blockIdx.x * 4 + wave;
    float ilox = soa[0 * N_DET + i], iloy = soa[1 * N_DET + i], iloz = soa[2 * N_DET + i];
    float ihix = soa[3 * N_DET + i], ihiy = soa[4 * N_DET + i], ihiz = soa[5 * N_DET + i];
    float ivol = soa[6 * N_DET + i];
    for (int w = 0; w < NW; ++w) {
        int j = w * 64 + lane;
        float lox = soa[0 * N_DET + j], loy = soa[1 * N_DET + j], loz = soa[2 * N_DET + j];
        float hix = soa[3 * N_DET + j], hiy = soa[4 * N_DET + j], hiz = soa[5 * N_DET + j];
        float vol = soa[6 * N_DET + j];
        float ix = fminf(ihix, hix) - fmaxf(ilox, lox); ix = fmaxf(ix, 0.0f);
        float iy = fminf(ihiy, hiy) - fmaxf(iloy, loy); iy = fmaxf(iy, 0.0f);
        float iz = fminf(ihiz, hiz) - fmaxf(iloz, loz); iz = fmaxf(iz, 0.0f);
        float inter = (ix * iy) * iz;                 // ((x*y)*z) like np.prod
        float uni = ivol + vol - inter;               // (vol_i+vol_j)-inter
        float iou = inter / (uni + EPS);              // IEEE div
        bool sb = (iou > IOU_TR) && (j > i);
        u64 m = __ballot(sb);
        if (lane == 0) T[(size_t)w * N_DET + i] = m;
    }
}

// K3: valid ballots + serial greedy scan + gated output, one 256-thread block.
// Wave 0 scans; per word w:
//   A: issue next word's 16 stream quads (consumed ~1000 cyc later)
//   B: diagonal closure on SALU; diag words = readlane(stream reg, w)
//   C: acc |= row & keepbit-mask (issue-bound VALU, scalar masks)
// Final keep bit k == decision mask for row k (strict upper-triangularity).

#define CHAIN1(Q, K) {                                                   \
    u64 d_ = rl64((Q), w_);                                              \
    u64 m_ = (u64)(((long long)(aw << (63 - (K)))) >> 63);               \
    aw &= ~(d_ & m_); }

#define CHAIN4(QQ, KB) CHAIN1(QQ.x, (KB)+0) CHAIN1(QQ.y, (KB)+1)         \
                       CHAIN1(QQ.z, (KB)+2) CHAIN1(QQ.w, (KB)+3)

#define ACC1(Q, K) {                                                     \
    u64 m_ = (u64)(((long long)(kw << (63 - (K)))) >> 63);               \
    acc |= ((Q) & m_); }

#define ACC4(QQ, KB) ACC1(QQ.x, (KB)+0) ACC1(QQ.y, (KB)+1)               \
                     ACC1(QQ.z, (KB)+2) ACC1(QQ.w, (KB)+3)

#define WORDBODY(CUR, NXT, W) {                                          \
    const int w_ = (W);                                                  \
    const ulonglong4* np_ = sp + (size_t)((w_ + 1 < NW) ? w_ + 1 : NW - 1) * 16; \
    NXT##0 = np_[0];  NXT##1 = np_[1];  NXT##2 = np_[2];  NXT##3 = np_[3];   \
    NXT##4 = np_[4];  NXT##5 = np_[5];  NXT##6 = np_[6];  NXT##7 = np_[7];   \
    NXT##8 = np_[8];  NXT##9 = np_[9];  NXT##10 = np_[10]; NXT##11 = np_[11];\
    NXT##12 = np_[12]; NXT##13 = np_[13]; NXT##14 = np_[14]; NXT##15 = np_[15];\
    __builtin_amdgcn_sched_barrier(0);                                   \
    u64 av = validl & ~acc;                                              \
    u64 aw = rl64(av, w_);                                               \
    CHAIN4(CUR##0, 0)   CHAIN4(CUR##1, 4)   CHAIN4(CUR##2, 8)            \
    CHAIN4(CUR##3, 12)  CHAIN4(CUR##4, 16)  CHAIN4(CUR##5, 20)           \
    CHAIN4(CUR##6, 24)  CHAIN4(CUR##7, 28)  CHAIN4(CUR##8, 32)           \
    CHAIN4(CUR##9, 36)  CHAIN4(CUR##10, 40) CHAIN4(CUR##11, 44)          \
    CHAIN4(CUR##12, 48) CHAIN4(CUR##13, 52) CHAIN4(CUR##14, 56)          \
    CHAIN4(CUR##15, 60)                                                  \
    u64 kw = aw;                                                         \
    s_keep[w_] = kw; /* all lanes, same addr, same value */              \
    ACC4(CUR##0, 0)   ACC4(CUR##1, 4)   ACC4(CUR##2, 8)   ACC4(CUR##3, 12)  \
    ACC4(CUR##4, 16)  ACC4(CUR##5, 20)  ACC4(CUR##6, 24)  ACC4(CUR##7, 28)  \
    ACC4(CUR##8, 32)  ACC4(CUR##9, 36)  ACC4(CUR##10, 40) ACC4(CUR##11, 44) \
    ACC4(CUR##12, 48) ACC4(CUR##13, 52) ACC4(CUR##14, 56) ACC4(CUR##15, 60) \
    __builtin_amdgcn_sched_barrier(0);                                   \
}

__global__ void __launch_bounds__(256, 1)
k_scanout(const u64* __restrict__ T, const float* __restrict__ rows,
          float* __restrict__ out) {
    __shared__ u64 s_valid[NW];
    __shared__ u64 s_keep[NW];
    const int tid = threadIdx.x;
    const int wv = tid >> 6;
    const int lane = tid & 63;

    // valid ballots over sorted scores: 4 waves x 16 words
    for (int w = wv * 16; w < wv * 16 + 16; ++w) {
        float scw = rows[(w * 64 + lane) * 8];
        u64 m = __ballot(scw >= SCORE_TR);
        if (lane == 0) s_valid[w] = m;
    }
    __syncthreads();

    if (wv == 0) {
        u64 validl = s_valid[lane];
        u64 acc = 0;
        const ulonglong4* sp = (const ulonglong4*)(T + (size_t)lane * N_DET);
        ulonglong4 A0 = sp[0],  A1 = sp[1],  A2 = sp[2],  A3 = sp[3],
                   A4 = sp[4],  A5 = sp[5],  A6 = sp[6],  A7 = sp[7],
                   A8 = sp[8],  A9 = sp[9],  A10 = sp[10], A11 = sp[11],
                   A12 = sp[12], A13 = sp[13], A14 = sp[14], A15 = sp[15];
        ulonglong4 B0, B1, B2, B3, B4, B5, B6, B7,
                   B8, B9, B10, B11, B12, B13, B14, B15;
        for (int w = 0; w < NW; w += 2) {
            WORDBODY(A, B, w)
            WORDBODY(B, A, w + 1)
        }
    }
    __syncthreads();

    // gated output: 256 threads x 16 rows, coalesced
    for (int n = 0; n < 16; ++n) {
        int i = n * 256 + tid;
        bool kp = (s_keep[i >> 6] >> (i & 63)) & 1ull;
        float4 a = kp ? ((const float4*)rows)[i * 2]     : make_float4(0.f, 0.f, 0.f, 0.f);
        float4 b = kp ? ((const float4*)rows)[i * 2 + 1] : make_float4(0.f, 0.f, 0.f, 0.f);
        ((float4*)out)[i * 2]     = a;
        ((float4*)out)[i * 2 + 1] = b;
    }
}

extern "C" void kernel_launch(void* const* d_in, const int* in_sizes, int n_in,
                              void* d_out, int out_size, void* d_ws, size_t ws_size,
                              hipStream_t stream) {
    const float* res = (const float*)d_in[0];
    float* out = (float*)d_out;

    float* rows = (float*)d_ws;                       // 32768 f32
    float* soa  = rows + N_DET * 8;                   // 28672 f32
    u64* T      = (u64*)(soa + 7 * N_DET);            // 64*4096 u64

    k_sort   <<<N_DET / 16, 256, 0, stream>>>(res, rows, soa);
    k_sup    <<<N_DET / 4, 256, 0, stream>>>(soa, T);
    k_scanout<<<1, 256, 0, stream>>>(T, rows, out);
}

// Round 6
// 67.402 us; speedup vs baseline: 4.5226x; 3.1546x over previous
//
#include <hip/hip_runtime.h>

typedef unsigned long long u64;

#define N_DET 4096
#define NW 64               // 4096 bits = 64 u64 words
#define IOU_TR 0.3f
#define SCORE_TR 0.1f
#define EPS 1e-9f

// ---------------------------------------------------------------------------
// ws layout:
//   rows : 4096*8 f32  (sorted detection rows)         128 KB
//   soa  : 7*4096 f32  (lox,loy,loz,hix,hiy,hiz,vol)   112 KB
//   A    : 64 u64      (bit i = suppression row i nonempty)
//   Trm  : 4096*64 u64 ROW-major bitmatrix; only nonempty rows are written.
// Scan: greedy over nonempty rows only (~1e2-1e3 expected). Row loads are
// independent of the decision chain -> fully prefetchable.
// ---------------------------------------------------------------------------

__device__ __forceinline__ u64 rl64(u64 v, int l) {
    unsigned lo = __builtin_amdgcn_readlane((unsigned)v, l);
    unsigned hi = __builtin_amdgcn_readlane((unsigned)(v >> 32), l);
    return ((u64)hi << 32) | lo;
}

// K1: stable descending rank sort (16 rows/block, 16 threads/row) + zero A.
__global__ void __launch_bounds__(256) k_sort(const float* __restrict__ res,
                                              float* __restrict__ rows,
                                              float* __restrict__ soa,
                                              u64* __restrict__ A) {
    __shared__ float s[N_DET];
    int tid = threadIdx.x;
    if (blockIdx.x == 0 && tid < 64) A[tid] = 0ull;
    for (int j = tid; j < N_DET; j += 256) s[j] = res[j * 8];
    __syncthreads();
    int r = tid >> 4, c = tid & 15;
    int gi = blockIdx.x * 16 + r;
    float sc = s[gi];
    int part = 0;
    int j0 = c * 256;
    for (int j = j0; j < j0 + 256; ++j) {
        float sj = s[j];
        part += (sj > sc) || (sj == sc && j < gi);
    }
    part += __shfl_xor(part, 1, 64);
    part += __shfl_xor(part, 2, 64);
    part += __shfl_xor(part, 4, 64);
    part += __shfl_xor(part, 8, 64);
    if (c == 0) {
        int rank = part;
        float4 a = *(const float4*)(res + gi * 8);
        float4 b = *(const float4*)(res + gi * 8 + 4);
        *(float4*)(rows + rank * 8)     = a;
        *(float4*)(rows + rank * 8 + 4) = b;
        // a = (score, class, cx, cy); b = (cz, dx, dy, dz)
        float cx = a.z, cy = a.w, cz = b.x, dx = b.y, dy = b.z, dz = b.w;
        soa[0 * N_DET + rank] = cx - dx * 0.5f;
        soa[1 * N_DET + rank] = cy - dy * 0.5f;
        soa[2 * N_DET + rank] = cz - dz * 0.5f;
        soa[3 * N_DET + rank] = cx + dx * 0.5f;
        soa[4 * N_DET + rank] = cy + dy * 0.5f;
        soa[5 * N_DET + rank] = cz + dz * 0.5f;
        soa[6 * N_DET + rank] = (dx * dy) * dz;   // np.prod order ((dx*dy)*dz)
    }
}

// K2: suppression rows. One wave per row i; row kept lane-distributed
// (lane w holds word w); only nonzero rows stored (one 512B store) + A bit.
__global__ void k_sup(const float* __restrict__ soa, u64* __restrict__ Trm,
                      u64* __restrict__ A) {
    int lane = threadIdx.x & 63;
    int wave = threadIdx.x >> 6;
    int i = blockIdx.x * 4 + wave;
    float ilox = soa[0 * N_DET + i], iloy = soa[1 * N_DET + i], iloz = soa[2 * N_DET + i];
    float ihix = soa[3 * N_DET + i], ihiy = soa[4 * N_DET + i], ihiz = soa[5 * N_DET + i];
    float ivol = soa[6 * N_DET + i];
    u64 rowword = 0, rowOr = 0;
    for (int w = 0; w < NW; ++w) {
        int j = w * 64 + lane;
        float lox = soa[0 * N_DET + j], loy = soa[1 * N_DET + j], loz = soa[2 * N_DET + j];
        float hix = soa[3 * N_DET + j], hiy = soa[4 * N_DET + j], hiz = soa[5 * N_DET + j];
        float vol = soa[6 * N_DET + j];
        float ix = fminf(ihix, hix) - fmaxf(ilox, lox); ix = fmaxf(ix, 0.0f);
        float iy = fminf(ihiy, hiy) - fmaxf(iloy, loy); iy = fmaxf(iy, 0.0f);
        float iz = fminf(ihiz, hiz) - fmaxf(iloz, loz); iz = fmaxf(iz, 0.0f);
        float inter = (ix * iy) * iz;                 // ((x*y)*z) like np.prod
        float uni = ivol + vol - inter;               // (vol_i+vol_j)-inter
        float iou = inter / (uni + EPS);              // IEEE div
        bool sb = (iou > IOU_TR) && (j > i);
        u64 m = __ballot(sb);
        rowOr |= m;
        rowword = (lane == w) ? m : rowword;
    }
    if (rowOr) {                                      // wave-uniform branch
        Trm[(size_t)i * NW + lane] = rowword;         // coalesced 512B store
        if (lane == 0) atomicOr(&A[i >> 6], 1ull << (i & 63));
    }
}

// K3: valid ballots + sparse greedy scan + gated output (one 256-thr block).
// Wave 0: build sorted nonempty-row list in LDS (prefix scan of A popcounts),
// then walk it with a 2x16-slot named-register load pipeline. Row loads are
// chain-independent; per-row chain = readlane(act) + mask + 64-bit andn.
// Sentinel index 4095 (row 4095 is provably empty) pads the list; its
// (unwritten) row data is masked out via si!=4095.

#define FIDX(V, GB) { V = (unsigned)s_nlist[(GB) + (lane & 15)]; }

#define IS1(V, P, S) { unsigned si_ = __builtin_amdgcn_readlane((V), (S)); \
    P##S = Trm[(size_t)si_ * NW + lane]; }

#define IS16(V, P) IS1(V,P,0) IS1(V,P,1) IS1(V,P,2) IS1(V,P,3)   \
    IS1(V,P,4) IS1(V,P,5) IS1(V,P,6) IS1(V,P,7)                  \
    IS1(V,P,8) IS1(V,P,9) IS1(V,P,10) IS1(V,P,11)                \
    IS1(V,P,12) IS1(V,P,13) IS1(V,P,14) IS1(V,P,15)

#define PR1(V, P, S) { unsigned si_ = __builtin_amdgcn_readlane((V), (S)); \
    u64 awd_ = rl64(act, (int)(si_ >> 6));                                 \
    u64 bit_ = (awd_ >> (si_ & 63u)) & 1ull;                               \
    u64 m_ = (0ull - bit_) & (0ull - (u64)(si_ != 4095u));                 \
    act &= ~(P##S & m_); }

#define PR16(V, P) PR1(V,P,0) PR1(V,P,1) PR1(V,P,2) PR1(V,P,3)   \
    PR1(V,P,4) PR1(V,P,5) PR1(V,P,6) PR1(V,P,7)                  \
    PR1(V,P,8) PR1(V,P,9) PR1(V,P,10) PR1(V,P,11)                \
    PR1(V,P,12) PR1(V,P,13) PR1(V,P,14) PR1(V,P,15)

__global__ void __launch_bounds__(256, 1)
k_scanout(const u64* __restrict__ Trm, const u64* __restrict__ A,
          const float* __restrict__ rows, float* __restrict__ out) {
    __shared__ u64 s_valid[NW];
    __shared__ u64 s_keep[NW];
    __shared__ unsigned short s_nlist[4224];
    const int tid = threadIdx.x;
    const int wv = tid >> 6;
    const int lane = tid & 63;

    // valid ballots over sorted scores: 4 waves x 16 words
    for (int w = wv * 16; w < wv * 16 + 16; ++w) {
        float scw = rows[(w * 64 + lane) * 8];
        u64 m = __ballot(scw >= SCORE_TR);
        if (lane == 0) s_valid[w] = m;
    }
    __syncthreads();

    if (wv == 0) {
        u64 act = s_valid[lane];
        u64 avA = A[lane];
        int pc = __popcll(avA);
        int inc = pc;
#pragma unroll
        for (int d = 1; d < 64; d <<= 1) {
            int t = __shfl_up(inc, d, 64);
            if (lane >= d) inc += t;
        }
        int exc = inc - pc;
        int nTotal = __shfl(inc, 63, 64);
        {   // emit this lane's nonempty-row indices (sorted globally)
            u64 m = avA; int o = exc;
            while (m) {
                int k = __builtin_ctzll(m); m &= m - 1;
                s_nlist[o++] = (unsigned short)(lane * 64 + k);
            }
        }
        int padded = (nTotal + 63) & ~63;
        for (int t = nTotal + lane; t < padded + 128; t += 64)
            s_nlist[t] = (unsigned short)4095;
        __threadfence_block();                 // wave-local LDS ordering

        if (padded > 0) {                      // padded is a multiple of 64
            u64 pa0,pa1,pa2,pa3,pa4,pa5,pa6,pa7,
                pa8,pa9,pa10,pa11,pa12,pa13,pa14,pa15;
            u64 pb0,pb1,pb2,pb3,pb4,pb5,pb6,pb7,
                pb8,pb9,pb10,pb11,pb12,pb13,pb14,pb15;
            unsigned iA0, iA1, iB0, iB1;
            FIDX(iA0, 0)  IS16(iA0, pa)
            FIDX(iB0, 16) IS16(iB0, pb)
            int g = 0;
            while (g < padded) {
                FIDX(iA1, g + 32)
                PR16(iA0, pa)                  // rows g..g+15
                IS16(iA1, pa)                  // issue g+32
                FIDX(iB1, g + 48)
                PR16(iB0, pb)                  // rows g+16..g+31
                IS16(iB1, pb)                  // issue g+48
                g += 32;
                if (g >= padded) break;
                FIDX(iA0, g + 32)
                PR16(iA1, pa)
                IS16(iA0, pa)
                FIDX(iB0, g + 48)
                PR16(iB1, pb)
                IS16(iB0, pb)
                g += 32;
            }
        }
        s_keep[lane] = act;                    // final act == keep mask
    }
    __syncthreads();

    // gated output: 256 threads x 16 rows, coalesced
    for (int n = 0; n < 16; ++n) {
        int i = n * 256 + tid;
        bool kp = (s_keep[i >> 6] >> (i & 63)) & 1ull;
        float4 a = kp ? ((const float4*)rows)[i * 2]     : make_float4(0.f, 0.f, 0.f, 0.f);
        float4 b = kp ? ((const float4*)rows)[i * 2 + 1] : make_float4(0.f, 0.f, 0.f, 0.f);
        ((float4*)out)[i * 2]     = a;
        ((float4*)out)[i * 2 + 1] = b;
    }
}

extern "C" void kernel_launch(void* const* d_in, const int* in_sizes, int n_in,
                              void* d_out, int out_size, void* d_ws, size_t ws_size,
                              hipStream_t stream) {
    const float* res = (const float*)d_in[0];
    float* out = (float*)d_out;

    float* rows = (float*)d_ws;                       // 32768 f32
    float* soa  = rows + N_DET * 8;                   // 28672 f32
    u64* A      = (u64*)(soa + 7 * N_DET);            // 64 u64
    u64* Trm    = A + NW;                             // 4096*64 u64 (row-major)

    k_sort   <<<N_DET / 16, 256, 0, stream>>>(res, rows, soa, A);
    k_sup    <<<N_DET / 4, 256, 0, stream>>>(soa, Trm, A);
    k_scanout<<<1, 256, 0, stream>>>(Trm, A, rows, out);
}